// Round 4
// baseline (104.832 us; speedup 1.0000x reference)
//
#include <hip/hip_runtime.h>
#include <math.h>

namespace {

constexpr int INF = 32;
constexpr int H   = 128;
constexpr int HH  = 64;
constexpr int ZD  = 192;   // H + HH
constexpr int SPB = 4;     // samples per block
constexpr float LNEPS = 1e-5f;

__device__ __forceinline__ float elu1(float v) {
    return v > 0.f ? v : (__expf(v) - 1.f);
}

// t[s][c] += sum_{r<DKq} act[s*ZD + r] * W0[r*LDW + c*64]
// W0 pre-offset to &W[row0*LDW + col]; act pre-offset to &buf[row0].
// NCOL columns 64 apart per thread; 8-row double-buffered weight prefetch,
// fully static indexing (rule #20). act reads are wave-uniform broadcasts.
template<int DKq, int LDW, int NCOL>
__device__ __forceinline__ void gemm2(const float* __restrict__ W0,
                                      const float* __restrict__ act,
                                      float (&t)[SPB][NCOL])
{
    if constexpr (DKq == 8) {
        float w[8 * NCOL];
#pragma unroll
        for (int r = 0; r < 8; ++r)
#pragma unroll
            for (int c = 0; c < NCOL; ++c) w[r * NCOL + c] = W0[r * LDW + c * 64];
#pragma unroll
        for (int rr = 0; rr < 8; rr += 4) {
#pragma unroll
            for (int s = 0; s < SPB; ++s) {
                const float4 hv = *reinterpret_cast<const float4*>(act + s * ZD + rr);
#pragma unroll
                for (int c = 0; c < NCOL; ++c) {
                    t[s][c] += hv.x * w[(rr + 0) * NCOL + c] + hv.y * w[(rr + 1) * NCOL + c]
                             + hv.z * w[(rr + 2) * NCOL + c] + hv.w * w[(rr + 3) * NCOL + c];
                }
            }
        }
    } else {
        constexpr int NCH = DKq / 8;
        static_assert((NCH & 1) == 0, "even chunk count");
        float wa[8 * NCOL], wb[8 * NCOL];
#pragma unroll
        for (int r = 0; r < 8; ++r)
#pragma unroll
            for (int c = 0; c < NCOL; ++c) wa[r * NCOL + c] = W0[r * LDW + c * 64];
#pragma unroll
        for (int ch = 0; ch < NCH; ch += 2) {
#pragma unroll
            for (int r = 0; r < 8; ++r)
#pragma unroll
                for (int c = 0; c < NCOL; ++c)
                    wb[r * NCOL + c] = W0[((ch + 1) * 8 + r) * LDW + c * 64];
#pragma unroll
            for (int rr = 0; rr < 8; rr += 4) {
#pragma unroll
                for (int s = 0; s < SPB; ++s) {
                    const float4 hv = *reinterpret_cast<const float4*>(act + s * ZD + ch * 8 + rr);
#pragma unroll
                    for (int c = 0; c < NCOL; ++c) {
                        t[s][c] += hv.x * wa[(rr + 0) * NCOL + c] + hv.y * wa[(rr + 1) * NCOL + c]
                                 + hv.z * wa[(rr + 2) * NCOL + c] + hv.w * wa[(rr + 3) * NCOL + c];
                    }
                }
            }
            if (ch + 2 < NCH) {
#pragma unroll
                for (int r = 0; r < 8; ++r)
#pragma unroll
                    for (int c = 0; c < NCOL; ++c)
                        wa[r * NCOL + c] = W0[((ch + 2) * 8 + r) * LDW + c * 64];
            }
#pragma unroll
            for (int rr = 0; rr < 8; rr += 4) {
#pragma unroll
                for (int s = 0; s < SPB; ++s) {
                    const float4 hv = *reinterpret_cast<const float4*>(act + s * ZD + (ch + 1) * 8 + rr);
#pragma unroll
                    for (int c = 0; c < NCOL; ++c) {
                        t[s][c] += hv.x * wb[(rr + 0) * NCOL + c] + hv.y * wb[(rr + 1) * NCOL + c]
                                 + hv.z * wb[(rr + 2) * NCOL + c] + hv.w * wb[(rr + 3) * NCOL + c];
                    }
                }
            }
        }
    }
}

__global__ __launch_bounds__(256, 4) void fused_sthgat(
    const float* __restrict__ x, const int* __restrict__ sid,
    const float* __restrict__ Wp, const float* __restrict__ bp,
    const float* __restrict__ emb, const float* __restrict__ gatW,
    const float* __restrict__ W1, const float* __restrict__ b1,
    const float* __restrict__ g1, const float* __restrict__ be1,
    const float* __restrict__ W2, const float* __restrict__ b2,
    const float* __restrict__ g2, const float* __restrict__ be2,
    const float* __restrict__ Wo, const float* __restrict__ bo,
    float* __restrict__ out)
{
    // P2: split-K partials [kq=4][s=4][col<=128]; lanes contiguous in col.
    __shared__ __align__(16) float P2[4 * SPB * H];
    __shared__ __align__(16) float buf0[SPB * ZD];
    __shared__ __align__(16) float buf1[SPB * ZD];

    const int tid  = threadIdx.x;
    const int lane = tid & 63;
    const int kq   = tid >> 6;     // GEMM role: K-quarter 0..3
    const int c    = tid & 63;     // GEMM role: column pair (c, c+64)
    const int sw   = tid >> 6;     // combine/LN role: sample 0..3 (wave = sample)
    const int sbase = blockIdx.x * SPB;

    // ---- stage x: 4 samples x 32 floats into buf0 (stride ZD) ----
    if (tid < SPB * INF) {
        buf0[(tid >> 5) * ZD + (tid & 31)] = x[(size_t)sbase * INF + tid];
    }
    __syncthreads();

    // ---- Wp: h0 = x @ Wp + bp  (buf0 -> buf1) ----
    {
        float t[SPB][2] = {};
        gemm2<8, H, 2>(Wp + (kq * 8) * H + c, buf0 + kq * 8, t);
#pragma unroll
        for (int s = 0; s < SPB; ++s) {
            P2[kq * (SPB * H) + s * H + c]      = t[s][0];
            P2[kq * (SPB * H) + s * H + c + 64] = t[s][1];
        }
        __syncthreads();
        float v0 = bp[c], v1 = bp[c + 64];
#pragma unroll
        for (int k = 0; k < 4; ++k) {
            v0 += P2[k * (SPB * H) + sw * H + c];
            v1 += P2[k * (SPB * H) + sw * H + c + 64];
        }
        buf1[sw * ZD + c]      = v0;
        buf1[sw * ZD + c + 64] = v1;
        __syncthreads();
    }

    // ---- GAT1: h = h + elu(h @ gW0)  (buf1 -> buf0) ----
    {
        float t[SPB][2] = {};
        gemm2<32, H, 2>(gatW + (kq * 32) * H + c, buf1 + kq * 32, t);
#pragma unroll
        for (int s = 0; s < SPB; ++s) {
            P2[kq * (SPB * H) + s * H + c]      = t[s][0];
            P2[kq * (SPB * H) + s * H + c + 64] = t[s][1];
        }
        __syncthreads();
        float v0 = 0.f, v1 = 0.f;
#pragma unroll
        for (int k = 0; k < 4; ++k) {
            v0 += P2[k * (SPB * H) + sw * H + c];
            v1 += P2[k * (SPB * H) + sw * H + c + 64];
        }
        buf0[sw * ZD + c]      = buf1[sw * ZD + c]      + elu1(v0);
        buf0[sw * ZD + c + 64] = buf1[sw * ZD + c + 64] + elu1(v1);
        __syncthreads();
    }

    // ---- GAT2: h = h + elu(h @ gW1)  (buf0 -> buf1) + emb concat ----
    {
        float t[SPB][2] = {};
        gemm2<32, H, 2>(gatW + H * H + (kq * 32) * H + c, buf0 + kq * 32, t);
#pragma unroll
        for (int s = 0; s < SPB; ++s) {
            P2[kq * (SPB * H) + s * H + c]      = t[s][0];
            P2[kq * (SPB * H) + s * H + c + 64] = t[s][1];
        }
        __syncthreads();
        float v0 = 0.f, v1 = 0.f;
#pragma unroll
        for (int k = 0; k < 4; ++k) {
            v0 += P2[k * (SPB * H) + sw * H + c];
            v1 += P2[k * (SPB * H) + sw * H + c + 64];
        }
        buf1[sw * ZD + c]      = buf0[sw * ZD + c]      + elu1(v0);
        buf1[sw * ZD + c + 64] = buf0[sw * ZD + c + 64] + elu1(v1);
        // z = [h2, emb[sid]]: wave sw fills its sample's 64 emb slots
        {
            const int st = sid[sbase + sw];
            buf1[sw * ZD + H + c] = emb[st * HH + c];
        }
        __syncthreads();
    }

    // ---- W1: u = z @ W1 + b1 ; LN1 (in-wave) + relu  (buf1 -> buf0) ----
    {
        float t[SPB][2] = {};
        gemm2<48, H, 2>(W1 + (kq * 48) * H + c, buf1 + kq * 48, t);
#pragma unroll
        for (int s = 0; s < SPB; ++s) {
            P2[kq * (SPB * H) + s * H + c]      = t[s][0];
            P2[kq * (SPB * H) + s * H + c + 64] = t[s][1];
        }
        __syncthreads();
        float u0 = b1[c], u1 = b1[c + 64];
#pragma unroll
        for (int k = 0; k < 4; ++k) {
            u0 += P2[k * (SPB * H) + sw * H + c];
            u1 += P2[k * (SPB * H) + sw * H + c + 64];
        }
        // LN over 128 channels; wave = sample, 2 channels/lane -> pure shfl
        float su = u0 + u1;
        float sq = u0 * u0 + u1 * u1;
#pragma unroll
        for (int off = 32; off >= 1; off >>= 1) {
            su += __shfl_xor(su, off, 64);
            sq += __shfl_xor(sq, off, 64);
        }
        const float m   = su * (1.f / H);
        const float var = sq * (1.f / H) - m * m;
        const float rs  = rsqrtf(var + LNEPS);
        buf0[sw * ZD + c]      = fmaxf((u0 - m) * rs * g1[c]      + be1[c],      0.f);
        buf0[sw * ZD + c + 64] = fmaxf((u1 - m) * rs * g1[c + 64] + be1[c + 64], 0.f);
        __syncthreads();
    }

    // ---- W2: v = z1 @ W2 + b2 ; LN2 (in-wave) ; out = z2 @ Wo + bo ----
    {
        float t[SPB][1] = {};
        gemm2<32, HH, 1>(W2 + (kq * 32) * HH + c, buf0 + kq * 32, t);
#pragma unroll
        for (int s = 0; s < SPB; ++s) {
            P2[kq * (SPB * HH) + s * HH + c] = t[s][0];
        }
        __syncthreads();
        float v = b2[c];
#pragma unroll
        for (int k = 0; k < 4; ++k) v += P2[k * (SPB * HH) + sw * HH + c];
        float su = v, sq = v * v;
#pragma unroll
        for (int off = 32; off >= 1; off >>= 1) {
            su += __shfl_xor(su, off, 64);
            sq += __shfl_xor(sq, off, 64);
        }
        const float m   = su * (1.f / HH);
        const float var = sq * (1.f / HH) - m * m;
        const float rs  = rsqrtf(var + LNEPS);
        const float z2  = fmaxf((v - m) * rs * g2[c] + be2[c], 0.f);
        float po = z2 * Wo[c];
#pragma unroll
        for (int off = 32; off >= 1; off >>= 1) po += __shfl_xor(po, off, 64);
        if (lane == 0) out[sbase + sw] = po + bo[0];
    }
}

}  // namespace

extern "C" void kernel_launch(void* const* d_in, const int* in_sizes, int n_in,
                              void* d_out, int out_size, void* d_ws, size_t ws_size,
                              hipStream_t stream)
{
    const float* x    = (const float*)d_in[0];
    const int*   sid  = (const int*)d_in[1];
    // d_in[2] edge_index, d_in[3] edge_weight, d_in[8] gat_a: unused —
    // node-uniform broadcast + row-softmax makes the GAT aggregation collapse
    // to elu(h @ W) independent of the graph.
    const float* Wp   = (const float*)d_in[4];
    const float* bp   = (const float*)d_in[5];
    const float* emb  = (const float*)d_in[6];
    const float* gatW = (const float*)d_in[7];
    const float* W1   = (const float*)d_in[9];
    const float* b1   = (const float*)d_in[10];
    const float* g1   = (const float*)d_in[11];
    const float* be1  = (const float*)d_in[12];
    const float* W2   = (const float*)d_in[13];
    const float* b2   = (const float*)d_in[14];
    const float* g2   = (const float*)d_in[15];
    const float* be2  = (const float*)d_in[16];
    const float* Wo   = (const float*)d_in[17];
    const float* bo   = (const float*)d_in[18];
    float* out = (float*)d_out;

    // 1024 blocks x 4 waves = 4096 waves = 4/SIMD, 4 independent
    // barrier domains per CU (vs 2 in round 3).
    dim3 grid(4096 / SPB);
    dim3 block(256);
    hipLaunchKernelGGL(fused_sthgat, grid, block, 0, stream,
                       x, sid, Wp, bp, emb, gatW, W1, b1, g1, be1,
                       W2, b2, g2, be2, Wo, bo, out);
}